// Round 12
// baseline (130.044 us; speedup 1.0000x reference)
//
#include <hip/hip_runtime.h>
#include <hip/hip_bf16.h>

#define HDIM 1024
#define SEQ 2048
#define BATCH 16
#define M_TOT (SEQ*BATCH)   // 32768
#define NBLK 4              // N split into 4 chunks of 256
#define BM 128
#define BN 256
#define BKT 64              // K-tile depth
#define NT (HDIM/BKT)       // 16 K-tiles

// prep_all grid layout (enc conversion ELIMINATED - fused into gemm)
#define NB_WE  ((HDIM*HDIM)/(8*256))    // 512
#define NB_QK  (HDIM)                   // 1024

typedef __attribute__((ext_vector_type(8))) short short8;
typedef __attribute__((ext_vector_type(4))) float f32x4;

typedef const void __attribute__((address_space(1))) gvoid_t;
typedef void __attribute__((address_space(3))) svoid_t;
#define GLD16(gp, lp) __builtin_amdgcn_global_load_lds((gvoid_t*)(gp), (svoid_t*)(lp), 16, 0, 0)
#define VMC(N) asm volatile("s_waitcnt vmcnt(" #N ")" ::: "memory")
#define LGKM0 asm volatile("s_waitcnt lgkmcnt(0)" ::: "memory")

static __device__ __forceinline__ unsigned short f2bf(float f) {
    unsigned int x = __float_as_uint(f);
    unsigned int r = (x + 0x7FFFu + ((x >> 16) & 1u)) >> 16;  // RNE
    return (unsigned short)r;
}

// ---------------- kernel 1: fused prep = conv_we + qk ----------------
__global__ __launch_bounds__(256) void prep_all(const float* __restrict__ hidden,
                                                const float* __restrict__ attn_w,
                                                const float* __restrict__ attn_b,
                                                float* __restrict__ q,
                                                __hip_bfloat16* __restrict__ web) {
    int bid = blockIdx.x;
    if (bid < NB_WE) {
        size_t i0 = ((size_t)bid * 256 + threadIdx.x) * 8;
        int n = (int)(i0 >> 10);
        int h = (int)(i0 & 1023);
        const float4* src = reinterpret_cast<const float4*>(attn_w + (size_t)n * (2 * HDIM) + HDIM + h);
        float4 a = src[0], b = src[1];
        union { unsigned short u[8]; short8 v; } cv;
        cv.u[0] = f2bf(a.x); cv.u[1] = f2bf(a.y); cv.u[2] = f2bf(a.z); cv.u[3] = f2bf(a.w);
        cv.u[4] = f2bf(b.x); cv.u[5] = f2bf(b.y); cv.u[6] = f2bf(b.z); cv.u[7] = f2bf(b.w);
        *reinterpret_cast<short8*>((unsigned short*)web + i0) = cv.v;
        return;
    }
    int k = bid - NB_WE;              // 0..1023
    int tid = threadIdx.x;
    const float* w = attn_w + (size_t)k * (2 * HDIM);
    float p[BATCH];
#pragma unroll
    for (int b = 0; b < BATCH; b++) p[b] = 0.f;
    for (int h = tid; h < HDIM; h += 256) {
        float wv = w[h];
#pragma unroll
        for (int b = 0; b < BATCH; b++) p[b] += hidden[b * HDIM + h] * wv;
    }
#pragma unroll
    for (int b = 0; b < BATCH; b++) {
        for (int off = 32; off; off >>= 1) p[b] += __shfl_down(p[b], off);
    }
    __shared__ float red[4][BATCH];
    int lane = tid & 63, wid = tid >> 6;
    if (lane == 0) {
#pragma unroll
        for (int b = 0; b < BATCH; b++) red[wid][b] = p[b];
    }
    __syncthreads();
    if (tid < BATCH) {
        float s = red[0][tid] + red[1][tid] + red[2][tid] + red[3][tid] + attn_b[k];
        q[(size_t)tid * HDIM + k] = s;
    }
}

// ---------------- kernel 2: 128x256 GEMM, fused fp32-A convert, 1 barrier/tile ----------------
// LDS (bytes): A[par] = par*16384 ([128 rows][128B] bf16); B[buf][h] = 32768 + buf*32768 + h*16384
// (256 rows x 128B, buf 0..2). Total 128KB. Swizzle involution per 128B row: slot16 ^= (row&7).
// Per tile t: read A(t) from A[t&1], B(t) from B[t%3].
//   C1: issue A-fp32(t+2) -> regs (av[t&1]);  C2: issue B(t+2) gload_lds -> B[(t+2)%3];
//   C3: VMC(8) [drains A(t+1)+B(t+1), keeps t+2's 8 in flight] + cvt/ds_write A(t+1)->A[(t+1)&1];
//   close: LGKM0 + one s_barrier.  av ping-pong gives ~1.25 tiles of latency cover.
__global__ __launch_bounds__(512, 2) void gemmf(const float* __restrict__ enc,
                                                const __hip_bfloat16* __restrict__ web,
                                                const float* __restrict__ qv,
                                                const float* __restrict__ score_w,
                                                float* __restrict__ part) {
    __shared__ __align__(16) char pool[131072];

    int tid = threadIdx.x;
    int lane = tid & 63;
    int wid = tid >> 6;        // 0..7
    int wr = wid >> 2;         // 0..1  M half (64 rows)
    int wc = wid & 3;          // 0..3  N quarter (64 cols)

    // XCD-bijective swizzle: 1024 blocks = 8 XCDs x 128; same-A-panel quartets contiguous per XCD
    int bid = blockIdx.x;
    int lin = (bid & 7) * 128 + (bid >> 3);
    int bm = lin >> 2;         // 0..255
    int bn = lin & 3;          // 0..3
    int m0 = bm * BM, n0 = bn * BN;

    // ---- B staging (gload_lds; pre-swizzled global source, linear LDS dest) ----
    int srow = tid >> 3;                                   // 0..63
    int scolb = (((tid & 7) ^ ((tid >> 3) & 7)) << 4);     // swizzled byte col
    const char* wb = (const char*)web;
    auto STG = [&](const char* g, int ldsoff) {
        GLD16(g + (size_t)srow * 2048 + scolb, pool + ldsoff + wid * 1024);
        GLD16(g + (size_t)(srow + 64) * 2048 + scolb, pool + ldsoff + 8192 + wid * 1024);
    };
    auto BPTR = [&](int kt, int h) { return wb + ((size_t)(n0 + h * 128) * HDIM + kt * BKT) * 2; };
#define BLDS(buf, h) (32768 + (buf) * 32768 + (h) * 16384)
    auto BSTG = [&](int kt, int buf) { STG(BPTR(kt, 0), BLDS(buf, 0)); STG(BPTR(kt, 1), BLDS(buf, 1)); };

    // ---- A fp32 load -> regs -> cvt -> swizzled ds_write ----
    int arow = tid >> 2;               // 0..127
    int a4 = tid & 3;                  // 16-f32 segment
    int ar7 = arow & 7;
    int s0b = ((a4 * 2) ^ ar7) << 4;
    int s1b = ((a4 * 2 + 1) ^ ar7) << 4;
    float4 av0[4], av1[4];
    auto ALD = [&](int kt, float4* av) {
        const float4* p = reinterpret_cast<const float4*>(enc + (size_t)(m0 + arow) * HDIM + kt * BKT + a4 * 16);
        av[0] = p[0]; av[1] = p[1]; av[2] = p[2]; av[3] = p[3];
    };
    auto CVT2 = [&](float4 lo, float4 hi) {
        union { __hip_bfloat162 b[4]; short8 s; } u;
        u.b[0] = __float22bfloat162_rn(make_float2(lo.x, lo.y));
        u.b[1] = __float22bfloat162_rn(make_float2(lo.z, lo.w));
        u.b[2] = __float22bfloat162_rn(make_float2(hi.x, hi.y));
        u.b[3] = __float22bfloat162_rn(make_float2(hi.z, hi.w));
        return u.s;
    };
    auto AWR = [&](float4* av, int par) {
        short8 w0 = CVT2(av[0], av[1]);
        short8 w1 = CVT2(av[2], av[3]);
        char* base = pool + par * 16384 + arow * 128;
        *reinterpret_cast<short8*>(base + s0b) = w0;
        *reinterpret_cast<short8*>(base + s1b) = w1;
    };

    // ---- fragment-read constants (swizzled ds_read addresses) ----
    int lq = lane & 15, lh = lane >> 4;
    int flip = (lq & 7) << 4;
    int pks0 = lq * 128 + ((lh * 16) ^ flip);
    int pks1 = lq * 128 + ((64 + lh * 16) ^ flip);
    int aFB = wr * 8192;                      // + par*16384 + mi*2048
    int bFB = 32768 + wc * 8192;              // + buf*32768 + nj*2048

    f32x4 acc[4][4];
#pragma unroll
    for (int i = 0; i < 4; i++)
#pragma unroll
        for (int j = 0; j < 4; j++) acc[i][j] = (f32x4)0.f;
    short8 br[4][2];

#define RD8(off) (*reinterpret_cast<const short8*>(pool + (off)))

    // cluster MI of tile: frag reads (B full at MI==0 from buf BB) + stage stmt + 8 MFMA
#define CLUSTER(MI, PAR, BB, STAGE_STMT)                                                  \
    {                                                                                     \
        if ((MI) == 0) {                                                                  \
            _Pragma("unroll") for (int nj = 0; nj < 4; ++nj) {                            \
                br[nj][0] = RD8(bFB + (BB) * 32768 + nj * 2048 + pks0);                   \
                br[nj][1] = RD8(bFB + (BB) * 32768 + nj * 2048 + pks1);                   \
            }                                                                             \
        }                                                                                 \
        short8 ak0 = RD8(aFB + (PAR) * 16384 + (MI) * 2048 + pks0);                       \
        short8 ak1 = RD8(aFB + (PAR) * 16384 + (MI) * 2048 + pks1);                       \
        STAGE_STMT;                                                                       \
        __builtin_amdgcn_s_setprio(1);                                                    \
        _Pragma("unroll") for (int nj = 0; nj < 4; ++nj) {                                \
            acc[MI][nj] = __builtin_amdgcn_mfma_f32_16x16x32_bf16(ak0, br[nj][0], acc[MI][nj], 0, 0, 0); \
            acc[MI][nj] = __builtin_amdgcn_mfma_f32_16x16x32_bf16(ak1, br[nj][1], acc[MI][nj], 0, 0, 0); \
        }                                                                                 \
        __builtin_amdgcn_s_setprio(0);                                                    \
    }

#define TILE(PAR, BB, S1, S2, S3)                                                         \
    {                                                                                     \
        CLUSTER(0, PAR, BB, S1);                                                          \
        CLUSTER(1, PAR, BB, S2);                                                          \
        CLUSTER(2, PAR, BB, S3);                                                          \
        CLUSTER(3, PAR, BB, );                                                            \
        LGKM0;                                                                            \
        __builtin_amdgcn_s_barrier();                                                     \
        __builtin_amdgcn_sched_barrier(0);                                                \
    }

    // ---- prologue: A(0)->regs->LDS0; B(0),B(1) staged; A(1)->regs in flight ----
    ALD(0, av0);
    BSTG(0, 0);
    BSTG(1, 1);
    VMC(8);            // drains A(0) fp32 loads (oldest 4); B(0),B(1) stay in flight
    AWR(av0, 0);       // A(0) -> Abuf0
    ALD(1, av1);
    VMC(8);            // drains B(0); leaves B(1)(4) + A(1)(4) = 8 in flight
    LGKM0;
    __builtin_amdgcn_s_barrier();
    __builtin_amdgcn_sched_barrier(0);

    // ---- main loop: 2 x 6 tiles (parity 2 x Bring 3 = period 6), then 4 peeled ----
#pragma unroll 1
    for (int J = 0; J < 2; ++J) {
        int t = 6 * J;
        TILE(0, 0, ALD(t + 2, av0), BSTG(t + 2, 2), { VMC(8); AWR(av1, 1); });
        TILE(1, 1, ALD(t + 3, av1), BSTG(t + 3, 0), { VMC(8); AWR(av0, 0); });
        TILE(0, 2, ALD(t + 4, av0), BSTG(t + 4, 1), { VMC(8); AWR(av1, 1); });
        TILE(1, 0, ALD(t + 5, av1), BSTG(t + 5, 2), { VMC(8); AWR(av0, 0); });
        TILE(0, 1, ALD(t + 6, av0), BSTG(t + 6, 0), { VMC(8); AWR(av1, 1); });
        TILE(1, 2, ALD(t + 7, av1), BSTG(t + 7, 1), { VMC(8); AWR(av0, 0); });
    }
    // tiles 12..15
    TILE(0, 0, ALD(14, av0), BSTG(14, 2), { VMC(8); AWR(av1, 1); });
    TILE(1, 1, ALD(15, av1), BSTG(15, 0), { VMC(8); AWR(av0, 0); });
    TILE(0, 2, , , { VMC(0); AWR(av1, 1); });
    TILE(1, 0, , , );

    // ---- fused epilogue (aliases pool; all buffers dead) ----
    float* q_lds = reinterpret_cast<float*>(pool);            // [16][256]
    float* sc_lds = reinterpret_cast<float*>(pool + 16384);   // [256]
    float* eng = reinterpret_cast<float*>(pool + 17408);      // [4][128]
    {
        int qb = tid >> 5;            // 0..15
        int kl = (tid & 31) * 8;      // 0..248
        const float4* src = reinterpret_cast<const float4*>(qv + (size_t)qb * HDIM + n0 + kl);
        float4 v0 = src[0], v1 = src[1];
        *reinterpret_cast<float4*>(&q_lds[qb * 256 + kl]) = v0;
        *reinterpret_cast<float4*>(&q_lds[qb * 256 + kl + 4]) = v1;
        if (tid < BN) sc_lds[tid] = score_w[n0 + tid];
    }
    __syncthreads();

#pragma unroll
    for (int mi = 0; mi < 4; ++mi) {
#pragma unroll
        for (int r = 0; r < 4; ++r) {
            int b = lh * 4 + r;       // row-within-16 == batch index (M = s*16 + b)
            float s = 0.f;
#pragma unroll
            for (int nj = 0; nj < 4; ++nj) {
                int kl = wc * 64 + nj * 16 + lq;
                float v = acc[mi][nj][r] + q_lds[b * 256 + kl];
                float t = 1.f - 2.f / (__expf(2.f * v) + 1.f);  // tanh(v)
                s += sc_lds[kl] * t;
            }
            for (int off = 1; off < 16; off <<= 1) s += __shfl_xor(s, off);
            if (lq == 0) eng[wc * 128 + wr * 64 + mi * 16 + b] = s;
        }
    }
    __syncthreads();
    if (tid < BM) {
        float s = eng[tid] + eng[128 + tid] + eng[256 + tid] + eng[384 + tid];
        part[(size_t)bn * M_TOT + m0 + tid] = s;
    }
#undef CLUSTER
#undef TILE
#undef RD8
#undef BLDS
}

// ---------------- kernel 3: reduce partials + mask + softmax over S ----------------
__global__ __launch_bounds__(256) void softmax_kernel(const float* __restrict__ part,
                                                      const int* __restrict__ mask,
                                                      float* __restrict__ out) {
    int b = blockIdx.x;
    int tid = threadIdx.x;
    __shared__ float e_lds[SEQ];
    __shared__ float red[4], red2[4];
    int lane = tid & 63, wid = tid >> 6;
    float lmax = -3.4e38f;
    for (int it = 0; it < SEQ / 256; ++it) {
        int s = it * 256 + tid;
        size_t m = (size_t)s * BATCH + b;
        float e = 0.f;
#pragma unroll
        for (int c = 0; c < NBLK; c++) e += part[(size_t)c * M_TOT + m];
        if (mask[(size_t)b * SEQ + s]) e = -1e12f;
        e_lds[s] = e;
        lmax = fmaxf(lmax, e);
    }
    for (int off = 32; off; off >>= 1) lmax = fmaxf(lmax, __shfl_xor(lmax, off));
    if (lane == 0) red[wid] = lmax;
    __syncthreads();
    float gmax = fmaxf(fmaxf(red[0], red[1]), fmaxf(red[2], red[3]));
    float lsum = 0.f;
    for (int it = 0; it < SEQ / 256; ++it) {
        int s = it * 256 + tid;
        float p = __expf(e_lds[s] - gmax);
        e_lds[s] = p;
        lsum += p;
    }
    for (int off = 32; off; off >>= 1) lsum += __shfl_xor(lsum, off);
    if (lane == 0) red2[wid] = lsum;
    __syncthreads();
    float inv = 1.f / (red2[0] + red2[1] + red2[2] + red2[3]);
    for (int it = 0; it < SEQ / 256; ++it) {
        int s = it * 256 + tid;
        out[(size_t)b * SEQ + s] = e_lds[s] * inv;
    }
}

extern "C" void kernel_launch(void* const* d_in, const int* in_sizes, int n_in,
                              void* d_out, int out_size, void* d_ws, size_t ws_size,
                              hipStream_t stream) {
    const float* hidden   = (const float*)d_in[0];
    const float* enc      = (const float*)d_in[1];
    const int*   seq_mask = (const int*)d_in[2];
    const float* attn_w   = (const float*)d_in[3];
    const float* attn_b   = (const float*)d_in[4];
    const float* score_w  = (const float*)d_in[5];
    float* out = (float*)d_out;

    char* ws = (char*)d_ws;
    float* q = (float*)ws;                                        // 64 KB
    __hip_bfloat16* web = (__hip_bfloat16*)(ws + 65536);          // 2 MB
    float* part = (float*)(ws + 65536 + 2 * 1024 * 1024);         // 512 KB

    prep_all<<<dim3(NB_WE + NB_QK), dim3(256), 0, stream>>>(hidden, attn_w, attn_b, q, web);
    gemmf<<<dim3(NBLK * (M_TOT / BM)), dim3(512), 0, stream>>>(enc, web, q, score_w, part);
    softmax_kernel<<<dim3(BATCH), dim3(256), 0, stream>>>(part, seq_mask, out);
}